// Round 8
// baseline (1038.134 us; speedup 1.0000x reference)
//
#include <hip/hip_runtime.h>

// GIN encoder: 3 x [fused gather+MLP(128->128->D) layer kernel, BN-stats] + segmented mean-pool
// N=100000 nodes, E=1600000 edges, G=128 graphs.
// R8: gather fused INTO the MFMA layer kernel. Per block: gather 64-node tile into
//     LDS A-tile (stride 136 shorts, <=2-way banks) -> GEMM1 -> per-wave XOR LDS
//     bounce -> GEMM2. Co-resident blocks overlap gather (fabric) with MFMA pipes.
//     Wa/Wb frags from L2 (no 32KB LDS staging -> 3-4 blocks/CU). Wave-reduced stats.

#define N_NODES 100000
#define N_EDGES 1600000
#define N_GRAPHS 128
#define BN_EPS 1e-5f
#define POOL_CHUNK 400
#define POOL_BLOCKS ((N_NODES + POOL_CHUNK - 1) / POOL_CHUNK)  // 250
#define NBUCKETS ((N_NODES + 511) / 512)                       // 196
#define PSC_CHUNK 4096
#define PSC_BLOCKS ((N_EDGES + PSC_CHUNK - 1) / PSC_CHUNK)     // 391
#define MLP_TILES ((N_NODES + 63) / 64)                        // 1563 = 521*3
#define LAYER_BLOCKS 521

typedef __attribute__((ext_vector_type(8))) short bf16x8;
typedef __attribute__((ext_vector_type(4))) float f32x4;

// ---------------------------------------------------------------- bf16 helpers
__device__ __forceinline__ unsigned short rne16(float f) {
  unsigned u = __float_as_uint(f);
  u += 0x7fffu + ((u >> 16) & 1u);
  return (unsigned short)(u >> 16);
}
__device__ __forceinline__ unsigned pack2(float lo, float hi) {
  unsigned a = __float_as_uint(lo); a += 0x7fffu + ((a >> 16) & 1u);
  unsigned b = __float_as_uint(hi); b += 0x7fffu + ((b >> 16) & 1u);
  return (a >> 16) | (b & 0xffff0000u);
}
__device__ __forceinline__ void bf2_to_f32(unsigned u, float& lo, float& hi) {
  lo = __uint_as_float(u << 16);
  hi = __uint_as_float(u & 0xffff0000u);
}
__device__ __forceinline__ void bf8_to_f32(uint4 u, float* f) {
  bf2_to_f32(u.x, f[0], f[1]);
  bf2_to_f32(u.y, f[2], f[3]);
  bf2_to_f32(u.z, f[4], f[5]);
  bf2_to_f32(u.w, f[6], f[7]);
}

// ---------------------------------------------------------------- weight prep (all 6 in one launch)
// W(K=128 x N fp32) -> B-operand frag-ordered bf16:
// flat = ((ntile*4 + kchunk)*64 + lane)*8 + j ; k = kchunk*32 + (lane>>4)*8 + j ; n = ntile*16 + (lane&15)
struct WPArgs {
  const float* w[6];
  unsigned short* o[6];
};
__global__ __launch_bounds__(256) void wprep_all_kernel(WPArgs wp) {
  int blk = blockIdx.x;
  int seg = (blk < 320) ? (blk >> 6) : 5;
  int base = (seg < 5) ? (seg << 6) : 320;
  int N = (seg == 5) ? 64 : 128;
  int f = (blk - base) * 256 + threadIdx.x;
  if (f >= 128 * N) return;
  int j = f & 7;
  int lane = (f >> 3) & 63;
  int t = f >> 9;
  int kchunk = t & 3, ntile = t >> 2;
  int k = kchunk * 32 + (lane >> 4) * 8 + j;
  int n = ntile * 16 + (lane & 15);
  wp.o[seg][f] = rne16(wp.w[seg][k * N + n]);
}

// ---------------------------------------------------------------- bucketed CSR build
__global__ __launch_bounds__(256) void bcount_kernel(const int* __restrict__ dst,
                                                     int* __restrict__ bcnt) {
  __shared__ int hist[NBUCKETS];
  int tid = threadIdx.x;
  for (int i = tid; i < NBUCKETS; i += 256) hist[i] = 0;
  __syncthreads();
  int e0 = blockIdx.x * PSC_CHUNK;
  int e1 = min(e0 + PSC_CHUNK, N_EDGES);
  for (int e = e0 + tid; e < e1; e += 256) atomicAdd(&hist[dst[e] >> 9], 1);
  __syncthreads();
  for (int i = tid; i < NBUCKETS; i += 256)
    if (hist[i]) atomicAdd(&bcnt[i], hist[i]);
}

__global__ __launch_bounds__(256) void bscan_kernel(const int* __restrict__ bcnt,
                                                    int* __restrict__ boff,
                                                    int* __restrict__ bcur,
                                                    int* __restrict__ row_ptr) {
  __shared__ int tmp[256];
  int tid = threadIdx.x;
  int c = (tid < NBUCKETS) ? bcnt[tid] : 0;
  tmp[tid] = c;
  __syncthreads();
  for (int off = 1; off < 256; off <<= 1) {
    int t = (tid >= off) ? tmp[tid - off] : 0;
    __syncthreads();
    tmp[tid] += t;
    __syncthreads();
  }
  if (tid < NBUCKETS) {
    int s = tmp[tid] - c;
    boff[tid] = s;
    bcur[tid] = s;
  }
  if (tid == 0) {
    boff[NBUCKETS] = N_EDGES;
    row_ptr[N_NODES] = N_EDGES;
  }
}

__global__ __launch_bounds__(256) void pscatter_kernel(const int* __restrict__ src,
                                                       const int* __restrict__ dst,
                                                       int* __restrict__ bcur,
                                                       unsigned* __restrict__ pairs) {
  __shared__ int hist[NBUCKETS];
  __shared__ int base[NBUCKETS];
  int tid = threadIdx.x;
  for (int i = tid; i < NBUCKETS; i += 256) hist[i] = 0;
  __syncthreads();
  int e0 = blockIdx.x * PSC_CHUNK;
  int e1 = min(e0 + PSC_CHUNK, N_EDGES);
  for (int e = e0 + tid; e < e1; e += 256) atomicAdd(&hist[dst[e] >> 9], 1);
  __syncthreads();
  for (int i = tid; i < NBUCKETS; i += 256) {
    int c = hist[i];
    base[i] = c ? atomicAdd(&bcur[i], c) : 0;
    hist[i] = 0;
  }
  __syncthreads();
  for (int e = e0 + tid; e < e1; e += 256) {
    int d = dst[e];
    int b = d >> 9;
    int slot = atomicAdd(&hist[b], 1);
    pairs[base[b] + slot] = ((unsigned)src[e] << 9) | (unsigned)(d & 511);
  }
}

__global__ __launch_bounds__(256) void bdeg_scan_kernel(const unsigned* __restrict__ pairs,
                                                        const int* __restrict__ boff,
                                                        int* __restrict__ row_ptr) {
  __shared__ int h[512];
  __shared__ int tmp[256];
  int tid = threadIdx.x, b = blockIdx.x;
  h[tid] = 0;
  h[tid + 256] = 0;
  __syncthreads();
  int p0 = boff[b], p1 = boff[b + 1];
  for (int p = p0 + tid; p < p1; p += 256) atomicAdd(&h[pairs[p] & 511u], 1);
  __syncthreads();
  int a0 = h[2 * tid], a1 = h[2 * tid + 1];
  int s = a0 + a1;
  tmp[tid] = s;
  __syncthreads();
  for (int off = 1; off < 256; off <<= 1) {
    int t = (tid >= off) ? tmp[tid - off] : 0;
    __syncthreads();
    tmp[tid] += t;
    __syncthreads();
  }
  int excl = tmp[tid] - s;
  int n0 = b << 9;
  int i0 = 2 * tid, i1 = 2 * tid + 1;
  if (n0 + i0 < N_NODES) row_ptr[n0 + i0] = p0 + excl;
  if (n0 + i1 < N_NODES) row_ptr[n0 + i1] = p0 + excl + a0;
}

__global__ __launch_bounds__(256) void bfill_kernel(const unsigned* __restrict__ pairs,
                                                    const int* __restrict__ boff,
                                                    const int* __restrict__ row_ptr,
                                                    int* __restrict__ adj) {
  __shared__ int cur[512];
  int tid = threadIdx.x, b = blockIdx.x;
  int n0 = b << 9;
  for (int i = tid; i < 512; i += 256)
    cur[i] = (n0 + i < N_NODES) ? row_ptr[n0 + i] : 0;
  __syncthreads();
  int p0 = boff[b], p1 = boff[b + 1];
  for (int p = p0 + tid; p < p1; p += 256) {
    unsigned pr = pairs[p];
    int pos = atomicAdd(&cur[pr & 511u], 1);
    adj[pos] = (int)(pr >> 9);
  }
}

// ---------------------------------------------------------------- fused layer kernel
// Per 64-row tile: gather (16 lanes/node, BN+ReLU on read for L0=false) -> LDS A-tile
// (stride 136 shorts) -> GEMM1 (Wa frags from L2) -> per-wave XOR LDS bounce ->
// GEMM2 (Wb frags from L2) -> bf16 store + wave-reduced column stats.
template <int N2, bool L0>
__global__ __launch_bounds__(256) void layer_kernel(
    const void* __restrict__ inv, const float* __restrict__ scale,
    const float* __restrict__ shift, const int* __restrict__ row_ptr,
    const int* __restrict__ adj, const unsigned short* __restrict__ Wfa,
    const unsigned short* __restrict__ Wfb, const float* __restrict__ ba,
    const float* __restrict__ bb, unsigned short* __restrict__ O,
    float* __restrict__ gstats, int M) {
  constexpr int NT2 = N2 / 16;
  __shared__ unsigned short sA[64 * 136];      // 17408 B, padded stride
  __shared__ unsigned short sH1[4][16 * 128];  // 16384 B, per-wave bounce
  __shared__ float sB[256];                    // ba(128) | bb(<=128)
  __shared__ float sSt[2 * N2];

  int tid = threadIdx.x;
  if (tid < 128) sB[tid] = ba[tid];
  else if (tid - 128 < N2) sB[tid] = bb[tid - 128];
  for (int i = tid; i < 2 * N2; i += 256) sSt[i] = 0.f;

  int lane = tid & 63, wave = tid >> 6;
  int m16 = lane & 15, quad = lane >> 4;
  int c8 = tid & 15;       // gather column group (16B)
  int grp = tid >> 4;      // gather node group 0..15
  unsigned short* h1 = &sH1[wave][0];
  const bf16x8* Wfa8 = (const bf16x8*)Wfa;
  const bf16x8* Wfb8 = (const bf16x8*)Wfb;

  float sc[8], sh[8];
  if (!L0) {
    float4 s0 = ((const float4*)scale)[c8 * 2], s1 = ((const float4*)scale)[c8 * 2 + 1];
    float4 h0 = ((const float4*)shift)[c8 * 2], h1v = ((const float4*)shift)[c8 * 2 + 1];
    sc[0] = s0.x; sc[1] = s0.y; sc[2] = s0.z; sc[3] = s0.w;
    sc[4] = s1.x; sc[5] = s1.y; sc[6] = s1.z; sc[7] = s1.w;
    sh[0] = h0.x; sh[1] = h0.y; sh[2] = h0.z; sh[3] = h0.w;
    sh[4] = h1v.x; sh[5] = h1v.y; sh[6] = h1v.z; sh[7] = h1v.w;
  }

  for (int t = blockIdx.x; t < MLP_TILES; t += gridDim.x) {
    int row0 = t * 64;

    // ---- gather phase: 4 sub-rounds of 16 nodes (16 lanes x 16B each)
    for (int sub = 0; sub < 4; ++sub) {
      int lrow = sub * 16 + grp;
      int n = row0 + lrow;
      float acc[8];
      if (n < M) {
        int beg = row_ptr[n], end = row_ptr[n + 1];
        if (L0) {
          const float* inf = (const float*)inv;
          const float4* p = (const float4*)(inf + (size_t)n * 128) + c8 * 2;
          float4 a = p[0], b = p[1];
          acc[0] = a.x; acc[1] = a.y; acc[2] = a.z; acc[3] = a.w;
          acc[4] = b.x; acc[5] = b.y; acc[6] = b.z; acc[7] = b.w;
          int k = beg;
          for (; k + 2 <= end; k += 2) {
            const float4* p0 = (const float4*)(inf + (size_t)adj[k] * 128) + c8 * 2;
            const float4* p1 = (const float4*)(inf + (size_t)adj[k + 1] * 128) + c8 * 2;
            float4 a0 = p0[0], b0 = p0[1], a1 = p1[0], b1 = p1[1];
            acc[0] += a0.x + a1.x; acc[1] += a0.y + a1.y;
            acc[2] += a0.z + a1.z; acc[3] += a0.w + a1.w;
            acc[4] += b0.x + b1.x; acc[5] += b0.y + b1.y;
            acc[6] += b0.z + b1.z; acc[7] += b0.w + b1.w;
          }
          for (; k < end; ++k) {
            const float4* p2 = (const float4*)(inf + (size_t)adj[k] * 128) + c8 * 2;
            float4 a = p2[0], b = p2[1];
            acc[0] += a.x; acc[1] += a.y; acc[2] += a.z; acc[3] += a.w;
            acc[4] += b.x; acc[5] += b.y; acc[6] += b.z; acc[7] += b.w;
          }
        } else {
          const unsigned short* inb = (const unsigned short*)inv;
          auto addf = [&](const float* f) {
#pragma unroll
            for (int j = 0; j < 8; ++j) acc[j] += fmaxf(fmaf(f[j], sc[j], sh[j]), 0.f);
          };
          {
            uint4 u = ((const uint4*)(inb + (size_t)n * 128))[c8];
            float f[8];
            bf8_to_f32(u, f);
#pragma unroll
            for (int j = 0; j < 8; ++j) acc[j] = fmaxf(fmaf(f[j], sc[j], sh[j]), 0.f);
          }
          int k = beg;
          for (; k + 4 <= end; k += 4) {
            int s0 = adj[k], s1 = adj[k + 1], s2 = adj[k + 2], s3 = adj[k + 3];
            uint4 u0 = ((const uint4*)(inb + (size_t)s0 * 128))[c8];
            uint4 u1 = ((const uint4*)(inb + (size_t)s1 * 128))[c8];
            uint4 u2 = ((const uint4*)(inb + (size_t)s2 * 128))[c8];
            uint4 u3 = ((const uint4*)(inb + (size_t)s3 * 128))[c8];
            float f[8];
            bf8_to_f32(u0, f); addf(f);
            bf8_to_f32(u1, f); addf(f);
            bf8_to_f32(u2, f); addf(f);
            bf8_to_f32(u3, f); addf(f);
          }
          for (; k < end; ++k) {
            uint4 u = ((const uint4*)(inb + (size_t)adj[k] * 128))[c8];
            float f[8];
            bf8_to_f32(u, f);
            addf(f);
          }
        }
      } else {
#pragma unroll
        for (int j = 0; j < 8; ++j) acc[j] = 0.f;
      }
      uint4 o;
      o.x = pack2(acc[0], acc[1]); o.y = pack2(acc[2], acc[3]);
      o.z = pack2(acc[4], acc[5]); o.w = pack2(acc[6], acc[7]);
      *(uint4*)&sA[lrow * 136 + c8 * 8] = o;
    }
    __syncthreads();

    // ---- MFMA phase
    int row0w = row0 + wave * 16;
    f32x4 acc2[NT2];
#pragma unroll
    for (int nt = 0; nt < NT2; ++nt) {
      float bv = sB[128 + nt * 16 + m16];
#pragma unroll
      for (int r = 0; r < 4; ++r) acc2[nt][r] = bv;
    }

#pragma unroll
    for (int kc2 = 0; kc2 < 4; ++kc2) {
      bf16x8 wb[NT2];
#pragma unroll
      for (int nt = 0; nt < NT2; ++nt) wb[nt] = Wfb8[(nt * 4 + kc2) * 64 + lane];

#pragma unroll
      for (int t2 = 0; t2 < 2; ++t2) {
        int n1t = 2 * kc2 + t2;
        float bv = sB[n1t * 16 + m16];
        f32x4 acc1 = {bv, bv, bv, bv};
#pragma unroll
        for (int kc = 0; kc < 4; ++kc) {
          bf16x8 av = *(const bf16x8*)&sA[(wave * 16 + m16) * 136 + (kc * 4 + quad) * 8];
          acc1 = __builtin_amdgcn_mfma_f32_16x16x32_bf16(
              av, Wfa8[(n1t * 4 + kc) * 64 + lane], acc1, 0, 0, 0);
        }
        int n1 = n1t * 16 + m16;
        int c = n1 >> 3;
#pragma unroll
        for (int r = 0; r < 4; ++r) {
          int mrow = quad * 4 + r;
          h1[mrow * 128 + (((c ^ mrow) & 15) << 3) + (n1 & 7)] =
              rne16(fmaxf(acc1[r], 0.f));
        }
      }
      int cR = kc2 * 4 + quad;
      bf16x8 hf = *(const bf16x8*)&h1[m16 * 128 + (((cR ^ m16) & 15) << 3)];
#pragma unroll
      for (int nt = 0; nt < NT2; ++nt)
        acc2[nt] = __builtin_amdgcn_mfma_f32_16x16x32_bf16(hf, wb[nt], acc2[nt], 0, 0, 0);
    }

    // ---- epilogue: store + wave-reduced stats
#pragma unroll
    for (int nt = 0; nt < NT2; ++nt) {
      float s = 0.f, ss = 0.f;
#pragma unroll
      for (int r = 0; r < 4; ++r) {
        int grow = row0w + quad * 4 + r;
        if (grow < M) {
          float v = acc2[nt][r];
          s += v;
          ss += v * v;
          O[(size_t)grow * N2 + nt * 16 + m16] = rne16(v);
        }
      }
      s += __shfl_xor(s, 16);
      s += __shfl_xor(s, 32);
      ss += __shfl_xor(ss, 16);
      ss += __shfl_xor(ss, 32);
      if (quad == 0) {
        atomicAdd(&sSt[nt * 16 + m16], s);
        atomicAdd(&sSt[N2 + nt * 16 + m16], ss);
      }
    }
    __syncthreads();  // protect sA reuse next tile (and sSt zero on first tile)
  }

  for (int i = tid; i < 2 * N2; i += 256) atomicAdd(&gstats[i], sSt[i]);
}

// ---------------------------------------------------------------- BN finalize: stats -> scale/shift
template <int DOUT>
__global__ void finalize_stats_kernel(float* __restrict__ stats, const float* __restrict__ g,
                                      const float* __restrict__ be) {
  int c = threadIdx.x;
  if (c < DOUT) {
    float inv_n = 1.0f / (float)N_NODES;
    float mean = stats[c] * inv_n;
    float var = stats[DOUT + c] * inv_n - mean * mean;
    float sc = g[c] * rsqrtf(var + BN_EPS);
    stats[2 * DOUT + c] = sc;
    stats[3 * DOUT + c] = be[c] - mean * sc;
  }
}

// ---------------------------------------------------------------- segmented mean pool (bf16 in, BN+ReLU fused)
__global__ __launch_bounds__(256) void pool_seg_kernel(
    const unsigned short* __restrict__ h, const float* __restrict__ scale,
    const float* __restrict__ shift, const int* __restrict__ batch,
    float* __restrict__ sums) {
  __shared__ float sacc[N_GRAPHS * 64];
  int tid = threadIdx.x;
  for (int i = tid; i < N_GRAPHS * 64; i += 256) sacc[i] = 0.f;

  int base = blockIdx.x * POOL_CHUNK;
  int last = min(base + POOL_CHUNK, N_NODES) - 1;
  int c4 = tid & 15;
  int r = tid >> 4;
  float4 sc = ((const float4*)scale)[c4];
  float4 sh = ((const float4*)shift)[c4];
  __syncthreads();

  float4 acc = make_float4(0.f, 0.f, 0.f, 0.f);
  int gcur = -1;
#pragma unroll 1
  for (int j = 0; j < POOL_CHUNK / 16; ++j) {
    int node = base + j * 16 + r;
    if (node >= N_NODES) break;
    int g = batch[node];
    if (g != gcur) {
      if (gcur >= 0) {
        float* p = &sacc[gcur * 64 + c4 * 4];
        atomicAdd(p + 0, acc.x); atomicAdd(p + 1, acc.y);
        atomicAdd(p + 2, acc.z); atomicAdd(p + 3, acc.w);
      }
      gcur = g;
      acc = make_float4(0.f, 0.f, 0.f, 0.f);
    }
    uint2 u = ((const uint2*)(h + (size_t)node * 64))[c4];
    float f0, f1, f2, f3;
    bf2_to_f32(u.x, f0, f1);
    bf2_to_f32(u.y, f2, f3);
    acc.x += fmaxf(fmaf(f0, sc.x, sh.x), 0.f);
    acc.y += fmaxf(fmaf(f1, sc.y, sh.y), 0.f);
    acc.z += fmaxf(fmaf(f2, sc.z, sh.z), 0.f);
    acc.w += fmaxf(fmaf(f3, sc.w, sh.w), 0.f);
  }
  if (gcur >= 0) {
    float* p = &sacc[gcur * 64 + c4 * 4];
    atomicAdd(p + 0, acc.x); atomicAdd(p + 1, acc.y);
    atomicAdd(p + 2, acc.z); atomicAdd(p + 3, acc.w);
  }
  __syncthreads();

  int gmin = batch[base];
  int gmax = batch[last];
  for (int g = gmin; g <= gmax; ++g)
    for (int i = tid; i < 64; i += 256)
      atomicAdd(&sums[g * 64 + i], sacc[g * 64 + i]);
}

// ---------------------------------------------------------------- divide by counts (binary search)
__global__ __launch_bounds__(256) void div_kernel(const float* __restrict__ sums,
                                                  const int* __restrict__ batch,
                                                  float* __restrict__ out) {
  int i = blockIdx.x * blockDim.x + threadIdx.x;
  if (i >= N_GRAPHS * 64) return;
  int g = i >> 6;
  int lo = 0, hi = N_NODES;
  while (lo < hi) { int m = (lo + hi) >> 1; if (batch[m] < g) lo = m + 1; else hi = m; }
  int lb = lo;
  lo = 0; hi = N_NODES;
  while (lo < hi) { int m = (lo + hi) >> 1; if (batch[m] <= g) lo = m + 1; else hi = m; }
  float cnt = (float)(lo - lb);
  out[i] = sums[i] / fmaxf(cnt, 1.0f);
}

// ---------------------------------------------------------------- launch
extern "C" void kernel_launch(void* const* d_in, const int* in_sizes, int n_in,
                              void* d_out, int out_size, void* d_ws, size_t ws_size,
                              hipStream_t stream) {
  const float* x = (const float*)d_in[0];
  const int* edge_index = (const int*)d_in[1];
  const int* batch = (const int*)d_in[2];
  const int* src = edge_index;
  const int* dst = edge_index + N_EDGES;

  const float* wa[3] = {(const float*)d_in[3], (const float*)d_in[9],  (const float*)d_in[15]};
  const float* ba[3] = {(const float*)d_in[4], (const float*)d_in[10], (const float*)d_in[16]};
  const float* wb[3] = {(const float*)d_in[5], (const float*)d_in[11], (const float*)d_in[17]};
  const float* bb[3] = {(const float*)d_in[6], (const float*)d_in[12], (const float*)d_in[18]};
  const float* gg[3] = {(const float*)d_in[7], (const float*)d_in[13], (const float*)d_in[19]};
  const float* be[3] = {(const float*)d_in[8], (const float*)d_in[14], (const float*)d_in[20]};

  // -------- workspace layout --------
  float* stats0 = (float*)d_ws;   // fp32 zeroed: stats0(512) stats1(512) stats2(256) psums(8192)
  float* stats1 = stats0 + 512;
  float* stats2 = stats1 + 512;
  float* psums = stats2 + 256;
  int* bcnt = (int*)(psums + (size_t)N_GRAPHS * 64);  // 256, zeroed with floats
  int* boff = bcnt + 256;
  int* bcur = boff + 256;
  int* row_ptr = bcur + 256;
  int* adj = row_ptr + 100004;
  unsigned* pairs = (unsigned*)(adj + N_EDGES);
  unsigned short* b0 = (unsigned short*)(pairs + N_EDGES);
  unsigned short* b1 = b0 + (size_t)N_NODES * 128;
  unsigned short* wf0 = b1 + (size_t)N_NODES * 128;
  unsigned short* wf[6];
  for (int i = 0; i < 6; ++i) wf[i] = wf0 + (size_t)i * 16384;
  size_t needed = (size_t)((char*)(wf0 + 6 * 16384) - (char*)d_ws);
  if (ws_size < needed) return;

  hipMemsetAsync(stats0, 0, 9472 * 4 + 256 * 4, stream);

  WPArgs wp;
  wp.w[0] = wa[0]; wp.w[1] = wb[0]; wp.w[2] = wa[1];
  wp.w[3] = wb[1]; wp.w[4] = wa[2]; wp.w[5] = wb[2];
  for (int i = 0; i < 6; ++i) wp.o[i] = wf[i];
  wprep_all_kernel<<<352, 256, 0, stream>>>(wp);

  bcount_kernel<<<PSC_BLOCKS, 256, 0, stream>>>(dst, bcnt);
  bscan_kernel<<<1, 256, 0, stream>>>(bcnt, boff, bcur, row_ptr);
  pscatter_kernel<<<PSC_BLOCKS, 256, 0, stream>>>(src, dst, bcur, pairs);
  bdeg_scan_kernel<<<NBUCKETS, 256, 0, stream>>>(pairs, boff, row_ptr);
  bfill_kernel<<<NBUCKETS, 256, 0, stream>>>(pairs, boff, row_ptr, adj);

  // ---- layer 0: in = x (fp32, no BN) -> b0
  layer_kernel<128, true><<<LAYER_BLOCKS, 256, 0, stream>>>(
      x, nullptr, nullptr, row_ptr, adj, wf[0], wf[1], ba[0], bb[0], b0, stats0, N_NODES);
  finalize_stats_kernel<128><<<1, 128, 0, stream>>>(stats0, gg[0], be[0]);

  // ---- layer 1: in = b0 (BN0 on read) -> b1
  layer_kernel<128, false><<<LAYER_BLOCKS, 256, 0, stream>>>(
      b0, stats0 + 256, stats0 + 384, row_ptr, adj, wf[2], wf[3], ba[1], bb[1], b1, stats1,
      N_NODES);
  finalize_stats_kernel<128><<<1, 128, 0, stream>>>(stats1, gg[1], be[1]);

  // ---- layer 2: in = b1 (BN1 on read) -> b0 (N2=64)
  layer_kernel<64, false><<<LAYER_BLOCKS, 256, 0, stream>>>(
      b1, stats1 + 256, stats1 + 384, row_ptr, adj, wf[4], wf[5], ba[2], bb[2], b0, stats2,
      N_NODES);
  finalize_stats_kernel<64><<<1, 64, 0, stream>>>(stats2, gg[2], be[2]);

  // ---- pool (BN2+ReLU fused) + divide
  pool_seg_kernel<<<POOL_BLOCKS, 256, 0, stream>>>(b0, stats2 + 128, stats2 + 192, batch, psums);
  div_kernel<<<32, 256, 0, stream>>>(psums, batch, (float*)d_out);
}

// Round 9
// 636.443 us; speedup vs baseline: 1.6311x; 1.6311x over previous
//
#include <hip/hip_runtime.h>

// GIN encoder: 3 x [CSR gather-agg bf16, fused MFMA MLP(128->128->D), BN-stats] + segmented mean-pool
// N=100000 nodes, E=1600000 edges, G=128 graphs.
// R9: revert R8 fusion (occupancy collapse starved the gather: 8% occ, 1.27 TB/s).
//     R7 structure + dispatch-count trims: finalize folded into consumer preambles;
//     CSR build 5->3 kernels (fixed-capacity buckets, fused bdeg+bfill with LDS-staged pairs).

#define N_NODES 100000
#define N_EDGES 1600000
#define N_GRAPHS 128
#define BN_EPS 1e-5f
#define POOL_CHUNK 400
#define POOL_BLOCKS ((N_NODES + POOL_CHUNK - 1) / POOL_CHUNK)  // 250
#define NBUCKETS ((N_NODES + 511) / 512)                       // 196
#define PSC_CHUNK 4096
#define PSC_BLOCKS ((N_EDGES + PSC_CHUNK - 1) / PSC_CHUNK)     // 391
#define PSC_CAP 10240                                          // slots per bucket (E[cnt]=8192, +22 sigma)
#define MLP_TILES ((N_NODES + 63) / 64)                        // 1563
#define INV_N (1.0f / (float)N_NODES)

typedef __attribute__((ext_vector_type(8))) short bf16x8;
typedef __attribute__((ext_vector_type(4))) float f32x4;

// ---------------------------------------------------------------- bf16 helpers
__device__ __forceinline__ unsigned short rne16(float f) {
  unsigned u = __float_as_uint(f);
  u += 0x7fffu + ((u >> 16) & 1u);
  return (unsigned short)(u >> 16);
}
__device__ __forceinline__ unsigned pack2(float lo, float hi) {
  unsigned a = __float_as_uint(lo); a += 0x7fffu + ((a >> 16) & 1u);
  unsigned b = __float_as_uint(hi); b += 0x7fffu + ((b >> 16) & 1u);
  return (a >> 16) | (b & 0xffff0000u);
}
__device__ __forceinline__ void bf2_to_f32(unsigned u, float& lo, float& hi) {
  lo = __uint_as_float(u << 16);
  hi = __uint_as_float(u & 0xffff0000u);
}
__device__ __forceinline__ void bf8_to_f32(uint4 u, float* f) {
  bf2_to_f32(u.x, f[0], f[1]);
  bf2_to_f32(u.y, f[2], f[3]);
  bf2_to_f32(u.z, f[4], f[5]);
  bf2_to_f32(u.w, f[6], f[7]);
}

// ---------------------------------------------------------------- weight prep (all 6 in one launch)
// W(K=128 x N fp32) -> B-operand frag-ordered bf16:
// flat = ((ntile*4 + kchunk)*64 + lane)*8 + j ; k = kchunk*32 + (lane>>4)*8 + j ; n = ntile*16 + (lane&15)
struct WPArgs {
  const float* w[6];
  unsigned short* o[6];
};
__global__ __launch_bounds__(256) void wprep_all_kernel(WPArgs wp) {
  int blk = blockIdx.x;
  int seg = (blk < 320) ? (blk >> 6) : 5;
  int base = (seg < 5) ? (seg << 6) : 320;
  int N = (seg == 5) ? 64 : 128;
  int f = (blk - base) * 256 + threadIdx.x;
  if (f >= 128 * N) return;
  int j = f & 7;
  int lane = (f >> 3) & 63;
  int t = f >> 9;
  int kchunk = t & 3, ntile = t >> 2;
  int k = kchunk * 32 + (lane >> 4) * 8 + j;
  int n = ntile * 16 + (lane & 15);
  wp.o[seg][f] = rne16(wp.w[seg][k * N + n]);
}

// ---------------------------------------------------------------- CSR build (3 kernels)
// 1) pscatter: block-aggregated scatter into fixed-capacity bucket slots (global cnt cursors)
__global__ __launch_bounds__(256) void pscatter_kernel(const int* __restrict__ src,
                                                       const int* __restrict__ dst,
                                                       int* __restrict__ cnt,
                                                       unsigned* __restrict__ pairs) {
  __shared__ int hist[NBUCKETS];
  __shared__ int base[NBUCKETS];
  int tid = threadIdx.x;
  for (int i = tid; i < NBUCKETS; i += 256) hist[i] = 0;
  __syncthreads();
  int e0 = blockIdx.x * PSC_CHUNK;
  int e1 = min(e0 + PSC_CHUNK, N_EDGES);
  for (int e = e0 + tid; e < e1; e += 256) atomicAdd(&hist[dst[e] >> 9], 1);
  __syncthreads();
  for (int i = tid; i < NBUCKETS; i += 256) {
    int c = hist[i];
    base[i] = c ? atomicAdd(&cnt[i], c) : 0;
    hist[i] = 0;  // becomes local cursor
  }
  __syncthreads();
  for (int e = e0 + tid; e < e1; e += 256) {
    int d = dst[e];
    int b = d >> 9;
    int slot = base[b] + atomicAdd(&hist[b], 1);
    if (slot < PSC_CAP)  // statistical safety clamp (never expected)
      pairs[(size_t)b * PSC_CAP + slot] = ((unsigned)src[e] << 9) | (unsigned)(d & 511);
  }
}

// 2) bscan: exclusive scan of per-bucket counts -> boff; row_ptr[N]=E
__global__ __launch_bounds__(256) void bscan_kernel(const int* __restrict__ cnt,
                                                    int* __restrict__ boff,
                                                    int* __restrict__ row_ptr) {
  __shared__ int tmp[256];
  int tid = threadIdx.x;
  int c = (tid < NBUCKETS) ? cnt[tid] : 0;
  tmp[tid] = c;
  __syncthreads();
  for (int off = 1; off < 256; off <<= 1) {
    int t = (tid >= off) ? tmp[tid - off] : 0;
    __syncthreads();
    tmp[tid] += t;
    __syncthreads();
  }
  if (tid < NBUCKETS) boff[tid] = tmp[tid] - c;
  if (tid == 0) row_ptr[N_NODES] = N_EDGES;
}

// 3) bbuild: per bucket, stage pairs in LDS once -> degree hist -> block scan ->
//    row_ptr write -> compacted adj fill (bucket-contiguous, L2-resident writes)
__global__ __launch_bounds__(256) void bbuild_kernel(const unsigned* __restrict__ pairs,
                                                     const int* __restrict__ cnt,
                                                     const int* __restrict__ boff,
                                                     int* __restrict__ row_ptr,
                                                     int* __restrict__ adj) {
  __shared__ unsigned spairs[PSC_CAP];  // 40 KB
  __shared__ int h[512];
  __shared__ int cur[512];
  __shared__ int tmp[256];
  int tid = threadIdx.x, b = blockIdx.x;
  int c = min(cnt[b], PSC_CAP);
  int p0 = boff[b];
  const unsigned* gp = pairs + (size_t)b * PSC_CAP;
  for (int p = tid; p < c; p += 256) spairs[p] = gp[p];
  h[tid] = 0;
  h[tid + 256] = 0;
  __syncthreads();
  for (int p = tid; p < c; p += 256) atomicAdd(&h[spairs[p] & 511u], 1);
  __syncthreads();
  int a0 = h[2 * tid], a1 = h[2 * tid + 1];
  int s = a0 + a1;
  tmp[tid] = s;
  __syncthreads();
  for (int off = 1; off < 256; off <<= 1) {
    int t = (tid >= off) ? tmp[tid - off] : 0;
    __syncthreads();
    tmp[tid] += t;
    __syncthreads();
  }
  int excl = tmp[tid] - s;
  int n0 = b << 9;
  if (n0 + 2 * tid < N_NODES) row_ptr[n0 + 2 * tid] = p0 + excl;
  if (n0 + 2 * tid + 1 < N_NODES) row_ptr[n0 + 2 * tid + 1] = p0 + excl + a0;
  cur[2 * tid] = p0 + excl;
  cur[2 * tid + 1] = p0 + excl + a0;
  __syncthreads();
  for (int p = tid; p < c; p += 256) {
    unsigned pr = spairs[p];
    int pos = atomicAdd(&cur[pr & 511u], 1);
    adj[pos] = (int)(pr >> 9);
  }
}

// ---------------------------------------------------------------- gather agg, layer 0 (fp32 in, bf16 out)
__global__ __launch_bounds__(256) void gather_l0_kernel(
    const float* __restrict__ in, const int* __restrict__ row_ptr,
    const int* __restrict__ adj, unsigned short* __restrict__ agg) {
  int gid = blockIdx.x * 256 + threadIdx.x;
  int n = gid >> 4;
  if (n >= N_NODES) return;
  int c8 = gid & 15;
  float acc[8];
  {
    const float4* p = (const float4*)(in + (size_t)n * 128) + c8 * 2;
    float4 a = p[0], b = p[1];
    acc[0] = a.x; acc[1] = a.y; acc[2] = a.z; acc[3] = a.w;
    acc[4] = b.x; acc[5] = b.y; acc[6] = b.z; acc[7] = b.w;
  }
  int beg = row_ptr[n], end = row_ptr[n + 1];
  for (int k = beg; k < end; ++k) {
    const float4* p = (const float4*)(in + (size_t)adj[k] * 128) + c8 * 2;
    float4 a = p[0], b = p[1];
    acc[0] += a.x; acc[1] += a.y; acc[2] += a.z; acc[3] += a.w;
    acc[4] += b.x; acc[5] += b.y; acc[6] += b.z; acc[7] += b.w;
  }
  uint4 o;
  o.x = pack2(acc[0], acc[1]); o.y = pack2(acc[2], acc[3]);
  o.z = pack2(acc[4], acc[5]); o.w = pack2(acc[6], acc[7]);
  ((uint4*)(agg + (size_t)n * 128))[c8] = o;
}

// ---------------------------------------------------------------- gather agg, layers 1/2
// bf16 in/out; BN scale/shift computed in-kernel from raw stats (sum | sumsq) + g + be.
__global__ __launch_bounds__(256) void gather_ln_kernel(
    const unsigned short* __restrict__ in, const float* __restrict__ stats,
    const float* __restrict__ g, const float* __restrict__ be,
    const int* __restrict__ row_ptr, const int* __restrict__ adj,
    unsigned short* __restrict__ agg) {
  int gid = blockIdx.x * 256 + threadIdx.x;
  int n = gid >> 4;
  if (n >= N_NODES) return;
  int c8 = gid & 15;
  float sc[8], sh[8];
#pragma unroll
  for (int j = 0; j < 8; ++j) {
    int col = c8 * 8 + j;
    float mean = stats[col] * INV_N;
    float var = stats[128 + col] * INV_N - mean * mean;
    float s = g[col] * rsqrtf(var + BN_EPS);
    sc[j] = s;
    sh[j] = be[col] - mean * s;
  }
  float acc[8];
  auto addf = [&](const float* f) {
#pragma unroll
    for (int j = 0; j < 8; ++j) acc[j] += fmaxf(fmaf(f[j], sc[j], sh[j]), 0.f);
  };
  int beg = row_ptr[n], end = row_ptr[n + 1];
  {
    uint4 u = ((const uint4*)(in + (size_t)n * 128))[c8];
    float f[8];
    bf8_to_f32(u, f);
#pragma unroll
    for (int j = 0; j < 8; ++j) acc[j] = fmaxf(fmaf(f[j], sc[j], sh[j]), 0.f);
  }
  int k = beg;
  for (; k + 4 <= end; k += 4) {
    int s0 = adj[k], s1 = adj[k + 1], s2 = adj[k + 2], s3 = adj[k + 3];
    uint4 u0 = ((const uint4*)(in + (size_t)s0 * 128))[c8];
    uint4 u1 = ((const uint4*)(in + (size_t)s1 * 128))[c8];
    uint4 u2 = ((const uint4*)(in + (size_t)s2 * 128))[c8];
    uint4 u3 = ((const uint4*)(in + (size_t)s3 * 128))[c8];
    float f[8];
    bf8_to_f32(u0, f); addf(f);
    bf8_to_f32(u1, f); addf(f);
    bf8_to_f32(u2, f); addf(f);
    bf8_to_f32(u3, f); addf(f);
  }
  for (; k < end; ++k) {
    uint4 u = ((const uint4*)(in + (size_t)adj[k] * 128))[c8];
    float f[8];
    bf8_to_f32(u, f);
    addf(f);
  }
  uint4 o;
  o.x = pack2(acc[0], acc[1]); o.y = pack2(acc[2], acc[3]);
  o.z = pack2(acc[4], acc[5]); o.w = pack2(acc[6], acc[7]);
  ((uint4*)(agg + (size_t)n * 128))[c8] = o;
}

// ---------------------------------------------------------------- fused MLP: O = mlp2(relu(mlp1(A)))
// (R7-verified) GEMM1 -> per-wave XOR-swizzled LDS bounce -> GEMM2; stats to gstats.
template <int N2>
__global__ __launch_bounds__(256) void fused_mlp_kernel(
    const unsigned short* __restrict__ A, const unsigned short* __restrict__ Wfa,
    const unsigned short* __restrict__ Wfb, const float* __restrict__ ba,
    const float* __restrict__ bb, unsigned short* __restrict__ O,
    float* __restrict__ gstats, int M, int ntiles) {
  constexpr int NT2 = N2 / 16;
  __shared__ unsigned short sWa[128 * 128];    // 32 KB, frag-ordered
  __shared__ unsigned short sH1[4][16 * 128];  // 16 KB, per-wave bounce
  __shared__ float sB[256];                    // ba(128) | bb(<=128)
  __shared__ float sSt[2 * N2];

  int tid = threadIdx.x;
  {
    const uint4* s = (const uint4*)Wfa;
    uint4* d = (uint4*)sWa;
    for (int i = tid; i < 128 * 128 / 8; i += 256) d[i] = s[i];
  }
  if (tid < 128) sB[tid] = ba[tid];
  else if (tid - 128 < N2) sB[tid] = bb[tid - 128];
  for (int i = tid; i < 2 * N2; i += 256) sSt[i] = 0.f;
  __syncthreads();

  int lane = tid & 63, wave = tid >> 6;
  int m16 = lane & 15, quad = lane >> 4;
  unsigned short* h1 = &sH1[wave][0];
  const bf16x8* sWa8 = (const bf16x8*)sWa;
  const bf16x8* Wfb8 = (const bf16x8*)Wfb;

  for (int t = blockIdx.x; t < ntiles; t += gridDim.x) {
    int row0 = t * 64 + wave * 16;
    int row = row0 + m16;

    bf16x8 a[4];
    if (row < M) {
      const bf16x8* Ar = (const bf16x8*)(A + (size_t)row * 128);
#pragma unroll
      for (int kc = 0; kc < 4; ++kc) a[kc] = Ar[kc * 4 + quad];
    } else {
#pragma unroll
      for (int kc = 0; kc < 4; ++kc)
#pragma unroll
        for (int j = 0; j < 8; ++j) a[kc][j] = 0;
    }

    f32x4 acc2[NT2];
#pragma unroll
    for (int nt = 0; nt < NT2; ++nt) {
      float bv = sB[128 + nt * 16 + m16];
#pragma unroll
      for (int r = 0; r < 4; ++r) acc2[nt][r] = bv;
    }

#pragma unroll
    for (int kc2 = 0; kc2 < 4; ++kc2) {
      bf16x8 wb[NT2];
#pragma unroll
      for (int nt = 0; nt < NT2; ++nt) wb[nt] = Wfb8[(nt * 4 + kc2) * 64 + lane];

#pragma unroll
      for (int t2 = 0; t2 < 2; ++t2) {
        int n1t = 2 * kc2 + t2;
        float bv = sB[n1t * 16 + m16];
        f32x4 acc1 = {bv, bv, bv, bv};
#pragma unroll
        for (int kc = 0; kc < 4; ++kc)
          acc1 = __builtin_amdgcn_mfma_f32_16x16x32_bf16(
              a[kc], sWa8[(n1t * 4 + kc) * 64 + lane], acc1, 0, 0, 0);
        int n1 = n1t * 16 + m16;
        int c = n1 >> 3;
#pragma unroll
        for (int r = 0; r < 4; ++r) {
          int mrow = quad * 4 + r;
          h1[mrow * 128 + (((c ^ mrow) & 15) << 3) + (n1 & 7)] =
              rne16(fmaxf(acc1[r], 0.f));
        }
      }
      int cR = kc2 * 4 + quad;
      bf16x8 hf = *(const bf16x8*)&h1[m16 * 128 + (((cR ^ m16) & 15) << 3)];
#pragma unroll
      for (int nt = 0; nt < NT2; ++nt)
        acc2[nt] = __builtin_amdgcn_mfma_f32_16x16x32_bf16(hf, wb[nt], acc2[nt], 0, 0, 0);
    }

#pragma unroll
    for (int nt = 0; nt < NT2; ++nt) {
      float s = 0.f, ss = 0.f;
#pragma unroll
      for (int r = 0; r < 4; ++r) {
        int grow = row0 + quad * 4 + r;
        if (grow < M) {
          float v = acc2[nt][r];
          s += v;
          ss += v * v;
          O[(size_t)grow * N2 + nt * 16 + m16] = rne16(v);
        }
      }
      atomicAdd(&sSt[nt * 16 + m16], s);
      atomicAdd(&sSt[N2 + nt * 16 + m16], ss);
    }
  }
  __syncthreads();
  for (int i = tid; i < 2 * N2; i += 256) atomicAdd(&gstats[i], sSt[i]);
}

// ---------------------------------------------------------------- segmented mean pool
// bf16 in; BN params computed in-kernel from raw stats (64 cols) + g + be.
__global__ __launch_bounds__(256) void pool_seg_kernel(
    const unsigned short* __restrict__ h, const float* __restrict__ stats,
    const float* __restrict__ g, const float* __restrict__ be,
    const int* __restrict__ batch, float* __restrict__ sums) {
  __shared__ float sacc[N_GRAPHS * 64];
  int tid = threadIdx.x;
  for (int i = tid; i < N_GRAPHS * 64; i += 256) sacc[i] = 0.f;

  int base = blockIdx.x * POOL_CHUNK;
  int last = min(base + POOL_CHUNK, N_NODES) - 1;
  int c4 = tid & 15;
  int r = tid >> 4;
  float4 sc, sh;
  {
    float m0 = stats[c4 * 4 + 0] * INV_N, m1 = stats[c4 * 4 + 1] * INV_N;
    float m2 = stats[c4 * 4 + 2] * INV_N, m3 = stats[c4 * 4 + 3] * INV_N;
    sc.x = g[c4 * 4 + 0] * rsqrtf(stats[64 + c4 * 4 + 0] * INV_N - m0 * m0 + BN_EPS);
    sc.y = g[c4 * 4 + 1] * rsqrtf(stats[64 + c4 * 4 + 1] * INV_N - m1 * m1 + BN_EPS);
    sc.z = g[c4 * 4 + 2] * rsqrtf(stats[64 + c4 * 4 + 2] * INV_N - m2 * m2 + BN_EPS);
    sc.w = g[c4 * 4 + 3] * rsqrtf(stats[64 + c4 * 4 + 3] * INV_N - m3 * m3 + BN_EPS);
    sh.x = be[c4 * 4 + 0] - m0 * sc.x;
    sh.y = be[c4 * 4 + 1] - m1 * sc.y;
    sh.z = be[c4 * 4 + 2] - m2 * sc.z;
    sh.w = be[c4 * 4 + 3] - m3 * sc.w;
  }
  __syncthreads();

  float4 acc = make_float4(0.f, 0.f, 0.f, 0.f);
  int gcur = -1;
#pragma unroll 1
  for (int j = 0; j < POOL_CHUNK / 16; ++j) {
    int node = base + j * 16 + r;
    if (node >= N_NODES) break;
    int gg = batch[node];
    if (gg != gcur) {
      if (gcur >= 0) {
        float* p = &sacc[gcur * 64 + c4 * 4];
        atomicAdd(p + 0, acc.x); atomicAdd(p + 1, acc.y);
        atomicAdd(p + 2, acc.z); atomicAdd(p + 3, acc.w);
      }
      gcur = gg;
      acc = make_float4(0.f, 0.f, 0.f, 0.f);
    }
    uint2 u = ((const uint2*)(h + (size_t)node * 64))[c4];
    float f0, f1, f2, f3;
    bf2_to_f32(u.x, f0, f1);
    bf2_to_f32(u.y, f2, f3);
    acc.x += fmaxf(fmaf(f0, sc.x, sh.x), 0.f);
    acc.y += fmaxf(fmaf(f1, sc.y, sh.y), 0.f);
    acc.z += fmaxf(fmaf(f2, sc.z, sh.z), 0.f);
    acc.w += fmaxf(fmaf(f3, sc.w, sh.w), 0.f);
  }
  if (gcur >= 0) {
    float* p = &sacc[gcur * 64 + c4 * 4];
    atomicAdd(p + 0, acc.x); atomicAdd(p + 1, acc.y);
    atomicAdd(p + 2, acc.z); atomicAdd(p + 3, acc.w);
  }
  __syncthreads();

  int gmin = batch[base];
  int gmax = batch[last];
  for (int gg = gmin; gg <= gmax; ++gg)
    for (int i = tid; i < 64; i += 256)
      atomicAdd(&sums[gg * 64 + i], sacc[gg * 64 + i]);
}

// ---------------------------------------------------------------- divide by counts (binary search)
__global__ __launch_bounds__(256) void div_kernel(const float* __restrict__ sums,
                                                  const int* __restrict__ batch,
                                                  float* __restrict__ out) {
  int i = blockIdx.x * blockDim.x + threadIdx.x;
  if (i >= N_GRAPHS * 64) return;
  int g = i >> 6;
  int lo = 0, hi = N_NODES;
  while (lo < hi) { int m = (lo + hi) >> 1; if (batch[m] < g) lo = m + 1; else hi = m; }
  int lb = lo;
  lo = 0; hi = N_NODES;
  while (lo < hi) { int m = (lo + hi) >> 1; if (batch[m] <= g) lo = m + 1; else hi = m; }
  float cnt = (float)(lo - lb);
  out[i] = sums[i] / fmaxf(cnt, 1.0f);
}

// ---------------------------------------------------------------- launch
extern "C" void kernel_launch(void* const* d_in, const int* in_sizes, int n_in,
                              void* d_out, int out_size, void* d_ws, size_t ws_size,
                              hipStream_t stream) {
  const float* x = (const float*)d_in[0];
  const int* edge_index = (const int*)d_in[1];
  const int* batch = (const int*)d_in[2];
  const int* src = edge_index;
  const int* dst = edge_index + N_EDGES;

  const float* wa[3] = {(const float*)d_in[3], (const float*)d_in[9],  (const float*)d_in[15]};
  const float* ba[3] = {(const float*)d_in[4], (const float*)d_in[10], (const float*)d_in[16]};
  const float* wb[3] = {(const float*)d_in[5], (const float*)d_in[11], (const float*)d_in[17]};
  const float* bb[3] = {(const float*)d_in[6], (const float*)d_in[12], (const float*)d_in[18]};
  const float* gg[3] = {(const float*)d_in[7], (const float*)d_in[13], (const float*)d_in[19]};
  const float* be[3] = {(const float*)d_in[8], (const float*)d_in[14], (const float*)d_in[20]};

  // -------- workspace layout --------
  float* stats0 = (float*)d_ws;   // fp32 zeroed: stats0(256) used as sum|sumsq -> need 256 floats;
  // keep 512 each for alignment/simplicity: [sum(128)|sumsq(128)|pad(256)]
  float* stats1 = stats0 + 512;
  float* stats2 = stats1 + 512;   // 256: [sum(64)|sumsq(64)|pad(128)]
  float* psums = stats2 + 256;    // 8192
  int* cnt = (int*)(psums + (size_t)N_GRAPHS * 64);  // 256, zeroed with floats
  int* boff = cnt + 256;                              // 256
  int* row_ptr = boff + 256;                          // 100004
  int* adj = row_ptr + 100004;
  unsigned* pairs = (unsigned*)(adj + N_EDGES);       // NBUCKETS*PSC_CAP
  unsigned short* b0 = (unsigned short*)(pairs + (size_t)NBUCKETS * PSC_CAP);
  unsigned short* b1 = b0 + (size_t)N_NODES * 128;
  unsigned short* wf0 = b1 + (size_t)N_NODES * 128;
  unsigned short* wf[6];
  for (int i = 0; i < 6; ++i) wf[i] = wf0 + (size_t)i * 16384;
  size_t needed = (size_t)((char*)(wf0 + 6 * 16384) - (char*)d_ws);
  if (ws_size < needed) return;

  // one memset covers stats+psums+cnt (contiguous)
  hipMemsetAsync(stats0, 0, 9472 * 4 + 256 * 4, stream);

  WPArgs wp;
  wp.w[0] = wa[0]; wp.w[1] = wb[0]; wp.w[2] = wa[1];
  wp.w[3] = wb[1]; wp.w[4] = wa[2]; wp.w[5] = wb[2];
  for (int i = 0; i < 6; ++i) wp.o[i] = wf[i];
  wprep_all_kernel<<<352, 256, 0, stream>>>(wp);

  // CSR build: 3 kernels
  pscatter_kernel<<<PSC_BLOCKS, 256, 0, stream>>>(src, dst, cnt, pairs);
  bscan_kernel<<<1, 256, 0, stream>>>(cnt, boff, row_ptr);
  bbuild_kernel<<<NBUCKETS, 256, 0, stream>>>(pairs, cnt, boff, row_ptr, adj);

  const int gather_blocks = (N_NODES * 16 + 255) / 256;
  const int fused_blocks = 768;

  // ---- layer 0: gather(x fp32) -> b0 ; fused MLP b0 -> b1 (stats0)
  gather_l0_kernel<<<gather_blocks, 256, 0, stream>>>(x, row_ptr, adj, b0);
  fused_mlp_kernel<128><<<fused_blocks, 256, 0, stream>>>(
      b0, wf[0], wf[1], ba[0], bb[0], b1, stats0, N_NODES, MLP_TILES);

  // ---- layer 1: gather(b1, BN0 from raw stats0) -> b0 ; fused MLP b0 -> b1 (stats1)
  gather_ln_kernel<<<gather_blocks, 256, 0, stream>>>(b1, stats0, gg[0], be[0],
                                                      row_ptr, adj, b0);
  fused_mlp_kernel<128><<<fused_blocks, 256, 0, stream>>>(
      b0, wf[2], wf[3], ba[1], bb[1], b1, stats1, N_NODES, MLP_TILES);

  // ---- layer 2: gather(b1, BN1 from raw stats1) -> b0 ; fused MLP b0 -> b1 (N2=64, stats2)
  gather_ln_kernel<<<gather_blocks, 256, 0, stream>>>(b1, stats1, gg[1], be[1],
                                                      row_ptr, adj, b0);
  fused_mlp_kernel<64><<<fused_blocks, 256, 0, stream>>>(
      b0, wf[4], wf[5], ba[2], bb[2], b1, stats2, N_NODES, MLP_TILES);

  // ---- pool (BN2 computed in-kernel) + divide
  pool_seg_kernel<<<POOL_BLOCKS, 256, 0, stream>>>(b1, stats2, gg[2], be[2], batch, psums);
  div_kernel<<<32, 256, 0, stream>>>(psums, batch, (float*)d_out);
}